// Round 2
// baseline (147.284 us; speedup 1.0000x reference)
//
#include <hip/hip_runtime.h>
#include <stdint.h>

// ---------- types ----------
typedef __attribute__((ext_vector_type(8))) __bf16 bf16x8;   // MFMA A/B frag (4 VGPRs)
typedef __attribute__((ext_vector_type(4))) float  floatx4;  // MFMA C/D frag
typedef __attribute__((ext_vector_type(4))) unsigned int uint4v;
typedef __attribute__((ext_vector_type(2))) unsigned int uint2v;
typedef __attribute__((ext_vector_type(4))) float  float4v;
typedef __attribute__((ext_vector_type(2))) float  float2v;

__device__ __forceinline__ unsigned short f2bf(float f) {
  union { float f; unsigned int u; } x; x.f = f;
  unsigned int r = x.u + 0x7fffu + ((x.u >> 16) & 1u);  // RNE
  return (unsigned short)(r >> 16);
}

// ------ kernel 1: start/end logits + init match region with b2 (fused) -------
__global__ __launch_bounds__(256) void logits_init_kernel(
    const float* __restrict__ hidden, const float* __restrict__ w_start,
    const float* __restrict__ b_start, const float* __restrict__ w_end,
    const float* __restrict__ b_end, const float* __restrict__ b2,
    float* __restrict__ out) {
  if (blockIdx.x >= 32) {  // init part (wave-uniform branch)
    float v = b2[0];
    int idx = ((blockIdx.x - 32) * 256 + threadIdx.x) * 4;  // 128 blks -> 131072
    *(float4v*)(out + 1024 + idx) = float4v{v, v, v, v};
    return;
  }
  const int tid  = threadIdx.x;
  const int lane = tid & 63;
  const int wv   = tid >> 6;
  const int wg   = blockIdx.x * 4 + wv;

  float wsv[12], wev[12];
#pragma unroll
  for (int t = 0; t < 12; ++t) {
    wsv[t] = w_start[lane + 64 * t];
    wev[t] = w_end[lane + 64 * t];
  }
  const float bs = b_start[0];
  const float be = b_end[0];

#pragma unroll
  for (int r = 0; r < 4; ++r) {
    int row = wg * 4 + r;
    const float* h = hidden + (size_t)row * 768;
    float ps = 0.f, pe = 0.f;
#pragma unroll
    for (int t = 0; t < 12; ++t) {
      float hv = h[lane + 64 * t];
      ps += hv * wsv[t];
      pe += hv * wev[t];
    }
#pragma unroll
    for (int off = 32; off >= 1; off >>= 1) {
      ps += __shfl_xor(ps, off, 64);
      pe += __shfl_xor(pe, off, 64);
    }
    if (lane == 0) { out[row] = ps + bs; out[512 + row] = pe + be; }
  }
}

// ---------------- kernel 2: proj v3 (R8, 32x64 tiles, 768 blocks) -------------
__global__ __launch_bounds__(256) void proj_kernel(
    const float* __restrict__ hidden, const float* __restrict__ w1,
    const float* __restrict__ b1, unsigned short* __restrict__ wsR,
    unsigned short* __restrict__ wsC) {
  __shared__ short As[4 * 32 * 8];  // (q*32+row)*8+j, q = k/8 in BK=32
  __shared__ short Bs[4 * 64 * 8];  // (q*64+n  )*8+j

  const int tid  = threadIdx.x;
  const int lane = tid & 63;
  const int wave = tid >> 6;
  const int wr = wave >> 1, wc = wave & 1;
  const int m0 = blockIdx.y * 32;
  const int n0g = blockIdx.x * 64;
  const bool isR = (n0g < 1536);
  const int kbase = isR ? 0 : 768;
  const int n0 = isR ? n0g : (n0g - 1536);
  const int q = lane >> 4, l15 = lane & 15;

  floatx4 acc0 = {}, acc1 = {};

  const int a_row = tid >> 3;
  const int a_s   = tid & 7;
  const int b_n   = tid & 63;
  const int b_kg  = tid >> 6;

  const float* hrow = hidden + (size_t)(m0 + a_row) * 768 + a_s * 4;
  const float* bcol = w1 + (size_t)(kbase + b_kg * 8) * 1536 + n0 + b_n;

  float4v hv = *(const float4v*)(hrow);
  float bv[8];
#pragma unroll
  for (int a = 0; a < 8; ++a) bv[a] = bcol[(size_t)a * 1536];

  const int aq = a_s >> 1;
  const int aj = (a_s & 1) * 4;

  for (int ko = 0; ko < 768; ko += 32) {
    uint2v au;
    au[0] = (unsigned int)f2bf(hv[0]) | ((unsigned int)f2bf(hv[1]) << 16);
    au[1] = (unsigned int)f2bf(hv[2]) | ((unsigned int)f2bf(hv[3]) << 16);
    *(uint2v*)(&As[(aq * 32 + a_row) * 8 + aj]) = au;
    uint4v pv;
#pragma unroll
    for (int a = 0; a < 4; ++a) {
      unsigned int lo = f2bf(bv[2 * a]);
      unsigned int hi = f2bf(bv[2 * a + 1]);
      pv[a] = lo | (hi << 16);
    }
    *(uint4v*)(&Bs[(b_kg * 64 + b_n) * 8]) = pv;
    __syncthreads();

    if (ko + 32 < 768) {
      hv = *(const float4v*)(hrow + ko + 32);
      const float* bp = bcol + (size_t)(ko + 32) * 1536;
#pragma unroll
      for (int a = 0; a < 8; ++a) bv[a] = bp[(size_t)a * 1536];
    }

    bf16x8 af  = *(const bf16x8*)(&As[(q * 32 + 16 * wr + l15) * 8]);
    bf16x8 bg0 = *(const bf16x8*)(&Bs[(q * 64 + 32 * wc + l15) * 8]);
    bf16x8 bg1 = *(const bf16x8*)(&Bs[(q * 64 + 32 * wc + 16 + l15) * 8]);
    acc0 = __builtin_amdgcn_mfma_f32_16x16x32_bf16(af, bg0, acc0, 0, 0, 0);
    acc1 = __builtin_amdgcn_mfma_f32_16x16x32_bf16(af, bg1, acc1, 0, 0, 0);
    __syncthreads();
  }

  unsigned short* outp = isR ? wsR : wsC;
#pragma unroll
  for (int ni = 0; ni < 2; ++ni) {
    const floatx4& ac = ni ? acc1 : acc0;
    int col = n0 + 32 * wc + 16 * ni + l15;
    float bias = isR ? b1[col] : 0.0f;
#pragma unroll
    for (int r = 0; r < 4; ++r) {
      int rowg = m0 + 16 * wr + q * 4 + r;
      outp[(size_t)rowg * 1536 + col] = f2bf(ac[r] + bias);
    }
  }
}

// ---------------- kernel 3: match — 2x4 register tiling, LDS-traffic cut -----
// LDS-bound before: 6 ds_read_b128 per 8 gelu per wave (45.4 us ~= LDS model).
// Now each thread computes 2 rows x 4 cols -> 14 ds_read_b128 per 64 gelu
// (3.4x less LDS traffic). Tile 32x64 per block, chunk=128 k, k split 4-way
// across blockIdx.z. Same gelu polynomial as verified kernel.
__device__ __forceinline__ float2v gelu2_acc(float2v x, float2v wv, float2v acc) {
  constexpr float C0 = 0.39103831f;
  constexpr float C1 = -0.05415410f;
  constexpr float C2 = 0.00461682f;
  constexpr float C3 = -1.51033e-4f;
  float2v xc;
  xc[0] = __builtin_amdgcn_fmed3f(x[0], -3.5f, 3.5f);
  xc[1] = __builtin_amdgcn_fmed3f(x[1], -3.5f, 3.5f);
  float2v u = xc * xc;                               // v_pk_mul_f32
  float2v p = __builtin_elementwise_fma(u,
      __builtin_elementwise_fma(u,
          __builtin_elementwise_fma(u, float2v{C3, C3}, float2v{C2, C2}),
          float2v{C1, C1}),
      float2v{C0, C0});                              // 3x v_pk_fma_f32
  float2v t = __builtin_elementwise_fma(xc, p, float2v{0.5f, 0.5f});
  float2v g = x * t;                                 // v_pk_mul_f32
  return __builtin_elementwise_fma(g, wv, acc);      // v_pk_fma_f32
}

// 8 k-steps of one (row, col) pair: 4 k-pairs through gelu2_acc
__device__ __forceinline__ void g8(float2v& acc, float4v r0, float4v r1,
                                   float4v c0, float4v c1,
                                   float4v w0, float4v w1) {
  acc = gelu2_acc(float2v{r0[0], r0[1]} + float2v{c0[0], c0[1]},
                  float2v{w0[0], w0[1]}, acc);
  acc = gelu2_acc(float2v{r0[2], r0[3]} + float2v{c0[2], c0[3]},
                  float2v{w0[2], w0[3]}, acc);
  acc = gelu2_acc(float2v{r1[0], r1[1]} + float2v{c1[0], c1[1]},
                  float2v{w1[0], w1[1]}, acc);
  acc = gelu2_acc(float2v{r1[2], r1[3]} + float2v{c1[2], c1[3]},
                  float2v{w1[2], w1[3]}, acc);
}

__device__ __forceinline__ void cvt8(uint4v v, float4v& lo4, float4v& hi4) {
  union { unsigned int u; float f; } t;
  float4v L, H;
  t.u = v[0] << 16;          L[0] = t.f;
  t.u = v[0] & 0xffff0000u;  L[1] = t.f;
  t.u = v[1] << 16;          L[2] = t.f;
  t.u = v[1] & 0xffff0000u;  L[3] = t.f;
  t.u = v[2] << 16;          H[0] = t.f;
  t.u = v[2] & 0xffff0000u;  H[1] = t.f;
  t.u = v[3] << 16;          H[2] = t.f;
  t.u = v[3] & 0xffff0000u;  H[3] = t.f;
  lo4 = L; hi4 = H;
}

__global__ __launch_bounds__(256) void match_kernel(
    const unsigned short* __restrict__ wsR,
    const unsigned short* __restrict__ wsC,
    const float* __restrict__ w2,
    float* __restrict__ outm) {
  __shared__ float Rs[32 * 132];   // 32 rows x 128 k, stride 132 (+4 pad)
  __shared__ float Cs[64 * 132];   // 64 cols x 128 k
  __shared__ float Ws[128];

  const int tid = threadIdx.x;
  const int jt = blockIdx.x;            // 0..3  -> 64 cols each
  const int it = blockIdx.y;            // 0..7  -> 32 rows each
  const int bz = blockIdx.z >> 2;       // batch
  const int kh = blockIdx.z & 3;        // k quarter (384 k each)

  const int rg  = tid >> 4;             // 0..15: rows {2rg, 2rg+1}
  const int cgl = tid & 15;             // cols {cgl, cgl+16, cgl+32, cgl+48}

  float2v accA0 = {}, accA1 = {}, accA2 = {}, accA3 = {};
  float2v accB0 = {}, accB1 = {}, accB2 = {}, accB3 = {};

  const int srow = tid >> 4;   // staging row base (0..15)
  const int sseg = tid & 15;   // 8-bf16 segment (0..15) -> k offset seg*8

  const float* rp0 = &Rs[(2 * rg + 0) * 132];
  const float* rp1 = &Rs[(2 * rg + 1) * 132];
  const float* cp0 = &Cs[(cgl +  0) * 132];
  const float* cp1 = &Cs[(cgl + 16) * 132];
  const float* cp2 = &Cs[(cgl + 32) * 132];
  const float* cp3 = &Cs[(cgl + 48) * 132];

  for (int kc = 0; kc < 3; ++kc) {
    const int Kb = kh * 384 + kc * 128;
    // ---- stage 32 R-rows + 64 C-rows x 128 k (bf16 -> f32) ----
#pragma unroll
    for (int a = 0; a < 2; ++a) {
      int row = srow + 16 * a;
      const unsigned short* g =
          wsR + (size_t)(bz * 256 + it * 32 + row) * 1536 + Kb + sseg * 8;
      uint4v v = *(const uint4v*)g;
      float4v lo, hi; cvt8(v, lo, hi);
      float* d = &Rs[row * 132 + sseg * 8];
      *(float4v*)d = lo;
      *(float4v*)(d + 4) = hi;
    }
#pragma unroll
    for (int a = 0; a < 4; ++a) {
      int row = srow + 16 * a;
      const unsigned short* g =
          wsC + (size_t)(bz * 256 + jt * 64 + row) * 1536 + Kb + sseg * 8;
      uint4v v = *(const uint4v*)g;
      float4v lo, hi; cvt8(v, lo, hi);
      float* d = &Cs[row * 132 + sseg * 8];
      *(float4v*)d = lo;
      *(float4v*)(d + 4) = hi;
    }
    if (tid < 128) Ws[tid] = w2[Kb + tid];
    __syncthreads();

    // ---- compute: 16 steps of 8 k ----
#pragma unroll 2
    for (int k = 0; k < 128; k += 8) {
      float4v ra0 = *(const float4v*)(rp0 + k);
      float4v ra1 = *(const float4v*)(rp0 + k + 4);
      float4v rb0 = *(const float4v*)(rp1 + k);
      float4v rb1 = *(const float4v*)(rp1 + k + 4);
      float4v w0  = *(const float4v*)(&Ws[k]);
      float4v w1  = *(const float4v*)(&Ws[k + 4]);
      {
        float4v c0 = *(const float4v*)(cp0 + k);
        float4v c1 = *(const float4v*)(cp0 + k + 4);
        g8(accA0, ra0, ra1, c0, c1, w0, w1);
        g8(accB0, rb0, rb1, c0, c1, w0, w1);
      }
      {
        float4v c0 = *(const float4v*)(cp1 + k);
        float4v c1 = *(const float4v*)(cp1 + k + 4);
        g8(accA1, ra0, ra1, c0, c1, w0, w1);
        g8(accB1, rb0, rb1, c0, c1, w0, w1);
      }
      {
        float4v c0 = *(const float4v*)(cp2 + k);
        float4v c1 = *(const float4v*)(cp2 + k + 4);
        g8(accA2, ra0, ra1, c0, c1, w0, w1);
        g8(accB2, rb0, rb1, c0, c1, w0, w1);
      }
      {
        float4v c0 = *(const float4v*)(cp3 + k);
        float4v c1 = *(const float4v*)(cp3 + k + 4);
        g8(accA3, ra0, ra1, c0, c1, w0, w1);
        g8(accB3, rb0, rb1, c0, c1, w0, w1);
      }
    }
    __syncthreads();
  }

  // ---- epilogue: 8 partial sums -> atomics ----
  const size_t rowA = (size_t)(bz * 256 + it * 32 + 2 * rg);
  const size_t base = rowA * 256 + jt * 64 + cgl;
  unsafeAtomicAdd(&outm[base +  0], accA0[0] + accA0[1]);
  unsafeAtomicAdd(&outm[base + 16], accA1[0] + accA1[1]);
  unsafeAtomicAdd(&outm[base + 32], accA2[0] + accA2[1]);
  unsafeAtomicAdd(&outm[base + 48], accA3[0] + accA3[1]);
  unsafeAtomicAdd(&outm[base + 256 +  0], accB0[0] + accB0[1]);
  unsafeAtomicAdd(&outm[base + 256 + 16], accB1[0] + accB1[1]);
  unsafeAtomicAdd(&outm[base + 256 + 32], accB2[0] + accB2[1]);
  unsafeAtomicAdd(&outm[base + 256 + 48], accB3[0] + accB3[1]);
}

// ---------------- launch ----------------
extern "C" void kernel_launch(void* const* d_in, const int* in_sizes, int n_in,
                              void* d_out, int out_size, void* d_ws, size_t ws_size,
                              hipStream_t stream) {
  const float* hidden  = (const float*)d_in[0];
  const float* w_start = (const float*)d_in[1];
  const float* b_start = (const float*)d_in[2];
  const float* w_end   = (const float*)d_in[3];
  const float* b_end   = (const float*)d_in[4];
  const float* w1      = (const float*)d_in[5];
  const float* b1      = (const float*)d_in[6];
  const float* w2      = (const float*)d_in[7];
  const float* b2      = (const float*)d_in[8];

  float* out = (float*)d_out;
  char* ws = (char*)d_ws;
  unsigned short* wsR = (unsigned short*)(ws);             // 1,572,864 B
  unsigned short* wsC = (unsigned short*)(ws + 1572864);   // 1,572,864 B (3 MB total)

  logits_init_kernel<<<dim3(160), dim3(256), 0, stream>>>(
      hidden, w_start, b_start, w_end, b_end, b2, out);
  proj_kernel<<<dim3(48, 16), dim3(256), 0, stream>>>(hidden, w1, b1, wsR, wsC);
  match_kernel<<<dim3(4, 8, 8), dim3(256), 0, stream>>>(wsR, wsC, w2, out + 1024);
}

// Round 3
// 131.479 us; speedup vs baseline: 1.1202x; 1.1202x over previous
//
#include <hip/hip_runtime.h>
#include <stdint.h>

// ---------- types ----------
typedef __attribute__((ext_vector_type(8))) __bf16 bf16x8;   // MFMA A/B frag (4 VGPRs)
typedef __attribute__((ext_vector_type(4))) float  floatx4;  // MFMA C/D frag
typedef __attribute__((ext_vector_type(4))) unsigned int uint4v;
typedef __attribute__((ext_vector_type(2))) unsigned int uint2v;
typedef __attribute__((ext_vector_type(4))) float  float4v;
typedef __attribute__((ext_vector_type(2))) float  float2v;

__device__ __forceinline__ unsigned short f2bf(float f) {
  union { float f; unsigned int u; } x; x.f = f;
  unsigned int r = x.u + 0x7fffu + ((x.u >> 16) & 1u);  // RNE
  return (unsigned short)(r >> 16);
}

// ------ kernel 1: start/end logits + init match region with b2 (fused) -------
__global__ __launch_bounds__(256) void logits_init_kernel(
    const float* __restrict__ hidden, const float* __restrict__ w_start,
    const float* __restrict__ b_start, const float* __restrict__ w_end,
    const float* __restrict__ b_end, const float* __restrict__ b2,
    float* __restrict__ out) {
  if (blockIdx.x >= 32) {  // init part (wave-uniform branch)
    float v = b2[0];
    int idx = ((blockIdx.x - 32) * 256 + threadIdx.x) * 4;  // 128 blks -> 131072
    *(float4v*)(out + 1024 + idx) = float4v{v, v, v, v};
    return;
  }
  const int tid  = threadIdx.x;
  const int lane = tid & 63;
  const int wv   = tid >> 6;
  const int wg   = blockIdx.x * 4 + wv;

  float wsv[12], wev[12];
#pragma unroll
  for (int t = 0; t < 12; ++t) {
    wsv[t] = w_start[lane + 64 * t];
    wev[t] = w_end[lane + 64 * t];
  }
  const float bs = b_start[0];
  const float be = b_end[0];

#pragma unroll
  for (int r = 0; r < 4; ++r) {
    int row = wg * 4 + r;
    const float* h = hidden + (size_t)row * 768;
    float ps = 0.f, pe = 0.f;
#pragma unroll
    for (int t = 0; t < 12; ++t) {
      float hv = h[lane + 64 * t];
      ps += hv * wsv[t];
      pe += hv * wev[t];
    }
#pragma unroll
    for (int off = 32; off >= 1; off >>= 1) {
      ps += __shfl_xor(ps, off, 64);
      pe += __shfl_xor(pe, off, 64);
    }
    if (lane == 0) { out[row] = ps + bs; out[512 + row] = pe + be; }
  }
}

// ---------------- kernel 2: proj v3 (R8, 32x64 tiles, 768 blocks) -------------
__global__ __launch_bounds__(256) void proj_kernel(
    const float* __restrict__ hidden, const float* __restrict__ w1,
    const float* __restrict__ b1, unsigned short* __restrict__ wsR,
    unsigned short* __restrict__ wsC) {
  __shared__ short As[4 * 32 * 8];  // (q*32+row)*8+j, q = k/8 in BK=32
  __shared__ short Bs[4 * 64 * 8];  // (q*64+n  )*8+j

  const int tid  = threadIdx.x;
  const int lane = tid & 63;
  const int wave = tid >> 6;
  const int wr = wave >> 1, wc = wave & 1;
  const int m0 = blockIdx.y * 32;
  const int n0g = blockIdx.x * 64;
  const bool isR = (n0g < 1536);
  const int kbase = isR ? 0 : 768;
  const int n0 = isR ? n0g : (n0g - 1536);
  const int q = lane >> 4, l15 = lane & 15;

  floatx4 acc0 = {}, acc1 = {};

  const int a_row = tid >> 3;
  const int a_s   = tid & 7;
  const int b_n   = tid & 63;
  const int b_kg  = tid >> 6;

  const float* hrow = hidden + (size_t)(m0 + a_row) * 768 + a_s * 4;
  const float* bcol = w1 + (size_t)(kbase + b_kg * 8) * 1536 + n0 + b_n;

  float4v hv = *(const float4v*)(hrow);
  float bv[8];
#pragma unroll
  for (int a = 0; a < 8; ++a) bv[a] = bcol[(size_t)a * 1536];

  const int aq = a_s >> 1;
  const int aj = (a_s & 1) * 4;

  for (int ko = 0; ko < 768; ko += 32) {
    uint2v au;
    au[0] = (unsigned int)f2bf(hv[0]) | ((unsigned int)f2bf(hv[1]) << 16);
    au[1] = (unsigned int)f2bf(hv[2]) | ((unsigned int)f2bf(hv[3]) << 16);
    *(uint2v*)(&As[(aq * 32 + a_row) * 8 + aj]) = au;
    uint4v pv;
#pragma unroll
    for (int a = 0; a < 4; ++a) {
      unsigned int lo = f2bf(bv[2 * a]);
      unsigned int hi = f2bf(bv[2 * a + 1]);
      pv[a] = lo | (hi << 16);
    }
    *(uint4v*)(&Bs[(b_kg * 64 + b_n) * 8]) = pv;
    __syncthreads();

    if (ko + 32 < 768) {
      hv = *(const float4v*)(hrow + ko + 32);
      const float* bp = bcol + (size_t)(ko + 32) * 1536;
#pragma unroll
      for (int a = 0; a < 8; ++a) bv[a] = bp[(size_t)a * 1536];
    }

    bf16x8 af  = *(const bf16x8*)(&As[(q * 32 + 16 * wr + l15) * 8]);
    bf16x8 bg0 = *(const bf16x8*)(&Bs[(q * 64 + 32 * wc + l15) * 8]);
    bf16x8 bg1 = *(const bf16x8*)(&Bs[(q * 64 + 32 * wc + 16 + l15) * 8]);
    acc0 = __builtin_amdgcn_mfma_f32_16x16x32_bf16(af, bg0, acc0, 0, 0, 0);
    acc1 = __builtin_amdgcn_mfma_f32_16x16x32_bf16(af, bg1, acc1, 0, 0, 0);
    __syncthreads();
  }

  unsigned short* outp = isR ? wsR : wsC;
#pragma unroll
  for (int ni = 0; ni < 2; ++ni) {
    const floatx4& ac = ni ? acc1 : acc0;
    int col = n0 + 32 * wc + 16 * ni + l15;
    float bias = isR ? b1[col] : 0.0f;
#pragma unroll
    for (int r = 0; r < 4; ++r) {
      int rowg = m0 + 16 * wr + q * 4 + r;
      outp[(size_t)rowg * 1536 + col] = f2bf(ac[r] + bias);
    }
  }
}

// ---------------- kernel 3: match — 2x4 tiling + REAL v_pk_*_f32 via asm -----
// R2 post-mortem: compiler scalarized float2 math (VALU-issue ~26us = scalar
// count), and 1 block/CU exposed latency. Fix: inline-asm v_pk_{add,mul,fma}_f32
// (VOP3P packed f32, full rate on CDNA4) -> 10 wave-instr per 2 elems, and
// grid 512 blocks (2/CU, 8 waves) via chunk=64, kh=8.
__device__ __forceinline__ float2v pk_add(float2v a, float2v b) {
  float2v d;
  asm("v_pk_add_f32 %0, %1, %2" : "=v"(d) : "v"(a), "v"(b));
  return d;
}
__device__ __forceinline__ float2v pk_mul(float2v a, float2v b) {
  float2v d;
  asm("v_pk_mul_f32 %0, %1, %2" : "=v"(d) : "v"(a), "v"(b));
  return d;
}
__device__ __forceinline__ float2v pk_fma(float2v a, float2v b, float2v c) {
  float2v d;
  asm("v_pk_fma_f32 %0, %1, %2, %3" : "=v"(d) : "v"(a), "v"(b), "v"(c));
  return d;
}

// gelu(x) ~= x*(0.5 + xc*p(xc^2)), xc = med3(x,-3.5,3.5). Same poly as the
// harness-verified kernel. 8 pk + 2 med3 per float2 pair.
__device__ __forceinline__ void gelu2_acc(float2v& acc, float2v r, float2v c,
                                          float2v wv) {
  const float2v C0v = {0.39103831f, 0.39103831f};
  const float2v C1v = {-0.05415410f, -0.05415410f};
  const float2v C2v = {0.00461682f, 0.00461682f};
  const float2v C3v = {-1.51033e-4f, -1.51033e-4f};
  const float2v H = {0.5f, 0.5f};
  float2v x = pk_add(r, c);
  float2v xc;
  xc[0] = __builtin_amdgcn_fmed3f(x[0], -3.5f, 3.5f);
  xc[1] = __builtin_amdgcn_fmed3f(x[1], -3.5f, 3.5f);
  float2v u = pk_mul(xc, xc);
  float2v p = pk_fma(u, pk_fma(u, pk_fma(u, C3v, C2v), C1v), C0v);
  float2v t = pk_fma(xc, p, H);
  float2v g = pk_mul(x, t);
  acc = pk_fma(g, wv, acc);
}

// 8 k-steps of one (row, col) pair
__device__ __forceinline__ void g8(float2v& acc, float4v r0, float4v r1,
                                   float4v c0, float4v c1,
                                   float4v w0, float4v w1) {
  gelu2_acc(acc, float2v{r0[0], r0[1]}, float2v{c0[0], c0[1]},
            float2v{w0[0], w0[1]});
  gelu2_acc(acc, float2v{r0[2], r0[3]}, float2v{c0[2], c0[3]},
            float2v{w0[2], w0[3]});
  gelu2_acc(acc, float2v{r1[0], r1[1]}, float2v{c1[0], c1[1]},
            float2v{w1[0], w1[1]});
  gelu2_acc(acc, float2v{r1[2], r1[3]}, float2v{c1[2], c1[3]},
            float2v{w1[2], w1[3]});
}

__device__ __forceinline__ void cvt8(uint4v v, float4v& lo4, float4v& hi4) {
  union { unsigned int u; float f; } t;
  float4v L, H;
  t.u = v[0] << 16;          L[0] = t.f;
  t.u = v[0] & 0xffff0000u;  L[1] = t.f;
  t.u = v[1] << 16;          L[2] = t.f;
  t.u = v[1] & 0xffff0000u;  L[3] = t.f;
  t.u = v[2] << 16;          H[0] = t.f;
  t.u = v[2] & 0xffff0000u;  H[1] = t.f;
  t.u = v[3] << 16;          H[2] = t.f;
  t.u = v[3] & 0xffff0000u;  H[3] = t.f;
  lo4 = L; hi4 = H;
}

__global__ __launch_bounds__(256) void match_kernel(
    const unsigned short* __restrict__ wsR,
    const unsigned short* __restrict__ wsC,
    const float* __restrict__ w2,
    float* __restrict__ outm) {
  __shared__ float Rs[32 * 68];   // 32 rows x 64 k, stride 68 (pad 4)
  __shared__ float Cs[64 * 68];   // 64 cols x 64 k
  __shared__ float Ws[64];

  const int tid = threadIdx.x;
  const int jt = blockIdx.x;            // 0..3  -> 64 cols each
  const int it = blockIdx.y;            // 0..7  -> 32 rows each
  const int bz = blockIdx.z >> 3;       // batch
  const int kh = blockIdx.z & 7;        // k eighth (192 k each)

  const int rg  = tid >> 4;             // rows {2rg, 2rg+1}
  const int cgl = tid & 15;             // cols {cgl, +16, +32, +48}

  float2v accA0 = {}, accA1 = {}, accA2 = {}, accA3 = {};
  float2v accB0 = {}, accB1 = {}, accB2 = {}, accB3 = {};

  const int srow = tid >> 3;   // 0..31
  const int sseg = tid & 7;    // 8-bf16 k-segment

  const float* rp0 = &Rs[(2 * rg + 0) * 68];
  const float* rp1 = &Rs[(2 * rg + 1) * 68];
  const float* cp0 = &Cs[(cgl +  0) * 68];
  const float* cp1 = &Cs[(cgl + 16) * 68];
  const float* cp2 = &Cs[(cgl + 32) * 68];
  const float* cp3 = &Cs[(cgl + 48) * 68];

  for (int kc = 0; kc < 3; ++kc) {
    const int Kb = kh * 192 + kc * 64;
    // ---- stage 32 R-rows + 64 C-rows x 64 k (bf16 -> f32) ----
    {
      const unsigned short* g =
          wsR + (size_t)(bz * 256 + it * 32 + srow) * 1536 + Kb + sseg * 8;
      uint4v v = *(const uint4v*)g;
      float4v lo, hi; cvt8(v, lo, hi);
      float* d = &Rs[srow * 68 + sseg * 8];
      *(float4v*)d = lo;
      *(float4v*)(d + 4) = hi;
    }
#pragma unroll
    for (int a = 0; a < 2; ++a) {
      int row = srow + 32 * a;
      const unsigned short* g =
          wsC + (size_t)(bz * 256 + jt * 64 + row) * 1536 + Kb + sseg * 8;
      uint4v v = *(const uint4v*)g;
      float4v lo, hi; cvt8(v, lo, hi);
      float* d = &Cs[row * 68 + sseg * 8];
      *(float4v*)d = lo;
      *(float4v*)(d + 4) = hi;
    }
    if (tid < 64) Ws[tid] = w2[Kb + tid];
    __syncthreads();

    // ---- compute: 8 steps of 8 k ----
#pragma unroll 2
    for (int k = 0; k < 64; k += 8) {
      float4v ra0 = *(const float4v*)(rp0 + k);
      float4v ra1 = *(const float4v*)(rp0 + k + 4);
      float4v rb0 = *(const float4v*)(rp1 + k);
      float4v rb1 = *(const float4v*)(rp1 + k + 4);
      float4v w0  = *(const float4v*)(&Ws[k]);
      float4v w1  = *(const float4v*)(&Ws[k + 4]);
      {
        float4v c0 = *(const float4v*)(cp0 + k);
        float4v c1 = *(const float4v*)(cp0 + k + 4);
        g8(accA0, ra0, ra1, c0, c1, w0, w1);
        g8(accB0, rb0, rb1, c0, c1, w0, w1);
      }
      {
        float4v c0 = *(const float4v*)(cp1 + k);
        float4v c1 = *(const float4v*)(cp1 + k + 4);
        g8(accA1, ra0, ra1, c0, c1, w0, w1);
        g8(accB1, rb0, rb1, c0, c1, w0, w1);
      }
      {
        float4v c0 = *(const float4v*)(cp2 + k);
        float4v c1 = *(const float4v*)(cp2 + k + 4);
        g8(accA2, ra0, ra1, c0, c1, w0, w1);
        g8(accB2, rb0, rb1, c0, c1, w0, w1);
      }
      {
        float4v c0 = *(const float4v*)(cp3 + k);
        float4v c1 = *(const float4v*)(cp3 + k + 4);
        g8(accA3, ra0, ra1, c0, c1, w0, w1);
        g8(accB3, rb0, rb1, c0, c1, w0, w1);
      }
    }
    __syncthreads();
  }

  // ---- epilogue: 8 partial sums -> atomics (8 contributions per address) ----
  const size_t rowA = (size_t)(bz * 256 + it * 32 + 2 * rg);
  const size_t base = rowA * 256 + jt * 64 + cgl;
  unsafeAtomicAdd(&outm[base +  0], accA0[0] + accA0[1]);
  unsafeAtomicAdd(&outm[base + 16], accA1[0] + accA1[1]);
  unsafeAtomicAdd(&outm[base + 32], accA2[0] + accA2[1]);
  unsafeAtomicAdd(&outm[base + 48], accA3[0] + accA3[1]);
  unsafeAtomicAdd(&outm[base + 256 +  0], accB0[0] + accB0[1]);
  unsafeAtomicAdd(&outm[base + 256 + 16], accB1[0] + accB1[1]);
  unsafeAtomicAdd(&outm[base + 256 + 32], accB2[0] + accB2[1]);
  unsafeAtomicAdd(&outm[base + 256 + 48], accB3[0] + accB3[1]);
}

// ---------------- launch ----------------
extern "C" void kernel_launch(void* const* d_in, const int* in_sizes, int n_in,
                              void* d_out, int out_size, void* d_ws, size_t ws_size,
                              hipStream_t stream) {
  const float* hidden  = (const float*)d_in[0];
  const float* w_start = (const float*)d_in[1];
  const float* b_start = (const float*)d_in[2];
  const float* w_end   = (const float*)d_in[3];
  const float* b_end   = (const float*)d_in[4];
  const float* w1      = (const float*)d_in[5];
  const float* b1      = (const float*)d_in[6];
  const float* w2      = (const float*)d_in[7];
  const float* b2      = (const float*)d_in[8];

  float* out = (float*)d_out;
  char* ws = (char*)d_ws;
  unsigned short* wsR = (unsigned short*)(ws);             // 1,572,864 B
  unsigned short* wsC = (unsigned short*)(ws + 1572864);   // 1,572,864 B (3 MB total)

  logits_init_kernel<<<dim3(160), dim3(256), 0, stream>>>(
      hidden, w_start, b_start, w_end, b_end, b2, out);
  proj_kernel<<<dim3(48, 16), dim3(256), 0, stream>>>(hidden, w1, b1, wsR, wsC);
  match_kernel<<<dim3(4, 8, 16), dim3(256), 0, stream>>>(wsR, wsC, w2, out + 1024);
}

// Round 5
// 123.614 us; speedup vs baseline: 1.1915x; 1.0636x over previous
//
#include <hip/hip_runtime.h>
#include <stdint.h>

// ---------- types ----------
typedef __attribute__((ext_vector_type(8))) __bf16 bf16x8;   // MFMA A/B frag (4 VGPRs)
typedef __attribute__((ext_vector_type(4))) float  floatx4;  // MFMA C/D frag
typedef __attribute__((ext_vector_type(4))) unsigned int uint4v;
typedef __attribute__((ext_vector_type(2))) unsigned int uint2v;
typedef __attribute__((ext_vector_type(4))) float  float4v;
typedef __attribute__((ext_vector_type(2))) _Float16 half2v;

__device__ __forceinline__ unsigned short f2bf(float f) {
  union { float f; unsigned int u; } x; x.f = f;
  unsigned int r = x.u + 0x7fffu + ((x.u >> 16) & 1u);  // RNE
  return (unsigned short)(r >> 16);
}

// ---------------- kernel 2+1 fused: proj + logits + out-init ------------------
// y < 16 : proj (unchanged R8 32x64 MFMA tiles)
// y == 16: x<32 -> start/end logits; x>=32 -> init match region with b2
__global__ __launch_bounds__(256) void proj_kernel(
    const float* __restrict__ hidden, const float* __restrict__ w1,
    const float* __restrict__ b1, unsigned short* __restrict__ wsR,
    unsigned short* __restrict__ wsC,
    const float* __restrict__ w_start, const float* __restrict__ b_start,
    const float* __restrict__ w_end, const float* __restrict__ b_end,
    const float* __restrict__ b2, float* __restrict__ out) {
  const int tid  = threadIdx.x;
  if (blockIdx.y == 16) {   // ---- fused logits + init (wave-uniform) ----
    if (blockIdx.x >= 32) {  // init 131072 floats with b2 over 16 blocks
      float v = b2[0];
      float4v vv = {v, v, v, v};
      int base = (blockIdx.x - 32) * 8192 + tid * 4;
#pragma unroll
      for (int itr = 0; itr < 8; ++itr)
        *(float4v*)(out + 1024 + base + itr * 1024) = vv;
      return;
    }
    const int lane = tid & 63;
    const int wv   = tid >> 6;
    const int wg   = blockIdx.x * 4 + wv;
    float wsv[12], wev[12];
#pragma unroll
    for (int t = 0; t < 12; ++t) {
      wsv[t] = w_start[lane + 64 * t];
      wev[t] = w_end[lane + 64 * t];
    }
    const float bs = b_start[0];
    const float be = b_end[0];
#pragma unroll
    for (int r = 0; r < 4; ++r) {
      int row = wg * 4 + r;
      const float* h = hidden + (size_t)row * 768;
      float ps = 0.f, pe = 0.f;
#pragma unroll
      for (int t = 0; t < 12; ++t) {
        float hv = h[lane + 64 * t];
        ps += hv * wsv[t];
        pe += hv * wev[t];
      }
#pragma unroll
      for (int off = 32; off >= 1; off >>= 1) {
        ps += __shfl_xor(ps, off, 64);
        pe += __shfl_xor(pe, off, 64);
      }
      if (lane == 0) { out[row] = ps + bs; out[512 + row] = pe + be; }
    }
    return;
  }

  // ---- proj proper ----
  __shared__ short As[4 * 32 * 8];  // (q*32+row)*8+j, q = k/8 in BK=32
  __shared__ short Bs[4 * 64 * 8];  // (q*64+n  )*8+j

  const int lane = tid & 63;
  const int wave = tid >> 6;
  const int wr = wave >> 1, wc = wave & 1;
  const int m0 = blockIdx.y * 32;
  const int n0g = blockIdx.x * 64;
  const bool isR = (n0g < 1536);
  const int kbase = isR ? 0 : 768;
  const int n0 = isR ? n0g : (n0g - 1536);
  const int q = lane >> 4, l15 = lane & 15;

  floatx4 acc0 = {}, acc1 = {};

  const int a_row = tid >> 3;
  const int a_s   = tid & 7;
  const int b_n   = tid & 63;
  const int b_kg  = tid >> 6;

  const float* hrow = hidden + (size_t)(m0 + a_row) * 768 + a_s * 4;
  const float* bcol = w1 + (size_t)(kbase + b_kg * 8) * 1536 + n0 + b_n;

  float4v hv = *(const float4v*)(hrow);
  float bv[8];
#pragma unroll
  for (int a = 0; a < 8; ++a) bv[a] = bcol[(size_t)a * 1536];

  const int aq = a_s >> 1;
  const int aj = (a_s & 1) * 4;

  for (int ko = 0; ko < 768; ko += 32) {
    uint2v au;
    au[0] = (unsigned int)f2bf(hv[0]) | ((unsigned int)f2bf(hv[1]) << 16);
    au[1] = (unsigned int)f2bf(hv[2]) | ((unsigned int)f2bf(hv[3]) << 16);
    *(uint2v*)(&As[(aq * 32 + a_row) * 8 + aj]) = au;
    uint4v pv;
#pragma unroll
    for (int a = 0; a < 4; ++a) {
      unsigned int lo = f2bf(bv[2 * a]);
      unsigned int hi = f2bf(bv[2 * a + 1]);
      pv[a] = lo | (hi << 16);
    }
    *(uint4v*)(&Bs[(b_kg * 64 + b_n) * 8]) = pv;
    __syncthreads();

    if (ko + 32 < 768) {
      hv = *(const float4v*)(hrow + ko + 32);
      const float* bp = bcol + (size_t)(ko + 32) * 1536;
#pragma unroll
      for (int a = 0; a < 8; ++a) bv[a] = bp[(size_t)a * 1536];
    }

    bf16x8 af  = *(const bf16x8*)(&As[(q * 32 + 16 * wr + l15) * 8]);
    bf16x8 bg0 = *(const bf16x8*)(&Bs[(q * 64 + 32 * wc + l15) * 8]);
    bf16x8 bg1 = *(const bf16x8*)(&Bs[(q * 64 + 32 * wc + 16 + l15) * 8]);
    acc0 = __builtin_amdgcn_mfma_f32_16x16x32_bf16(af, bg0, acc0, 0, 0, 0);
    acc1 = __builtin_amdgcn_mfma_f32_16x16x32_bf16(af, bg1, acc1, 0, 0, 0);
    __syncthreads();
  }

  unsigned short* outp = isR ? wsR : wsC;
#pragma unroll
  for (int ni = 0; ni < 2; ++ni) {
    const floatx4& ac = ni ? acc1 : acc0;
    int col = n0 + 32 * wc + 16 * ni + l15;
    float bias = isR ? b1[col] : 0.0f;
#pragma unroll
    for (int r = 0; r < 4; ++r) {
      int rowg = m0 + 16 * wr + q * 4 + r;
      outp[(size_t)rowg * 1536 + col] = f2bf(ac[r] + bias);
    }
  }
}

// ---------------- kernel 3: match — packed f16 (v_pk_*_f16 + v_dot2_f32_f16) -
// R3 post-mortem: v_pk_*_f32 is HALF-RATE on CDNA4 (157 TF f32 ceiling), so
// the f32 gelu floor is ~23 us VALU. f16 packed is genuinely 2x rate (314 TF)
// and v_dot2_f32_f16 gives f32 accumulation of f16 pairs in 1 instr.
// bf16 -> f16 is EXACT (mantissa 7 < 10), so only in-loop rounding is new.
// LDS holds f16: DS traffic halves. kc=1, kh=24, grid 1536 = 6 blocks/CU.
__device__ __forceinline__ void gelu_pair(float& acc, unsigned int ru,
                                          unsigned int cu, unsigned int wu) {
  const half2v C3 = {(_Float16)-1.51033e-4f, (_Float16)-1.51033e-4f};
  const half2v C2 = {(_Float16)0.00461682f, (_Float16)0.00461682f};
  const half2v C1 = {(_Float16)-0.05415410f, (_Float16)-0.05415410f};
  const half2v C0 = {(_Float16)0.39103831f, (_Float16)0.39103831f};
  const half2v HI = {(_Float16)3.5f, (_Float16)3.5f};
  const half2v LO = {(_Float16)-3.5f, (_Float16)-3.5f};
  const half2v HALF = {(_Float16)0.5f, (_Float16)0.5f};
  half2v r = __builtin_bit_cast(half2v, ru);
  half2v c = __builtin_bit_cast(half2v, cu);
  half2v w = __builtin_bit_cast(half2v, wu);
  half2v x = r + c;                                     // v_pk_add_f16
  half2v xc = __builtin_elementwise_min(
      __builtin_elementwise_max(x, LO), HI);            // v_pk_max/min_f16
  half2v u = xc * xc;                                   // v_pk_mul_f16
  half2v p = __builtin_elementwise_fma(u,
      __builtin_elementwise_fma(u,
          __builtin_elementwise_fma(u, C3, C2), C1), C0);  // 3x v_pk_fma_f16
  half2v t = __builtin_elementwise_fma(xc, p, HALF);    // v_pk_fma_f16
  half2v g = x * t;                                     // v_pk_mul_f16
  acc = __builtin_amdgcn_fdot2(g, w, acc, false);       // v_dot2_f32_f16
}

// 8 bf16 (uint4) -> 8 f16 (uint4); bf16->f16 exact, cvt_pkrtz rounding moot
__device__ __forceinline__ uint4v bf8_to_h8(uint4v v) {
  uint4v o;
#pragma unroll
  for (int a = 0; a < 4; ++a) {
    union { unsigned int u; float f; } lo, hi;
    lo.u = v[a] << 16;
    hi.u = v[a] & 0xffff0000u;
    auto h = __builtin_amdgcn_cvt_pkrtz(lo.f, hi.f);   // __fp16x2
    o[a] = __builtin_bit_cast(unsigned int, h);
  }
  return o;
}

__global__ __launch_bounds__(256) void match_kernel(
    const unsigned short* __restrict__ wsR,
    const unsigned short* __restrict__ wsC,
    const float* __restrict__ w2,
    float* __restrict__ outm) {
  // f16 tiles, row stride 72 f16 = 36 uints = 144 B
  // R-read rows {0,2,4,6}+base -> banks {0-3,8-11,16-19,24-27}: conflict-free
  // C-read cols stride 144 B -> 2-way (free per m136)
  __shared__ unsigned int RsU[32 * 36];   // 4608 B
  __shared__ unsigned int CsU[64 * 36];   // 9216 B
  __shared__ unsigned int WsU[32];        //  128 B

  const int tid = threadIdx.x;
  const int jt = blockIdx.x;              // 0..3 -> 64 cols
  const int it = blockIdx.y;              // 0..7 -> 32 rows
  const int bz = blockIdx.z / 24;         // batch
  const int kh = blockIdx.z % 24;         // k 1/24th (64 k)
  const int Kb = kh * 64;

  const int rg  = tid >> 4;               // rows {2rg, 2rg+1}
  const int cgl = tid & 15;               // cols {cgl, +16, +32, +48}

  float accA0 = 0.f, accA1 = 0.f, accA2 = 0.f, accA3 = 0.f;
  float accB0 = 0.f, accB1 = 0.f, accB2 = 0.f, accB3 = 0.f;

  // ---- stage 32 R-rows + 64 C-rows x 64 k (bf16 -> f16) ----
  const int srow = tid >> 3;   // 0..31
  const int sseg = tid & 7;    // 8-elem k-segment
  {
    const unsigned short* g =
        wsR + (size_t)(bz * 256 + it * 32 + srow) * 1536 + Kb + sseg * 8;
    *(uint4v*)(RsU + srow * 36 + sseg * 4) = bf8_to_h8(*(const uint4v*)g);
  }
#pragma unroll
  for (int a = 0; a < 2; ++a) {
    int row = srow + 32 * a;
    const unsigned short* g =
        wsC + (size_t)(bz * 256 + jt * 64 + row) * 1536 + Kb + sseg * 8;
    *(uint4v*)(CsU + row * 36 + sseg * 4) = bf8_to_h8(*(const uint4v*)g);
  }
  if (tid < 32) {
    auto h = __builtin_amdgcn_cvt_pkrtz(w2[Kb + 2 * tid], w2[Kb + 2 * tid + 1]);
    WsU[tid] = __builtin_bit_cast(unsigned int, h);
  }
  __syncthreads();

  const unsigned int* rap = RsU + (2 * rg + 0) * 36;
  const unsigned int* rbp = RsU + (2 * rg + 1) * 36;
  const unsigned int* c0p = CsU + (cgl +  0) * 36;
  const unsigned int* c1p = CsU + (cgl + 16) * 36;
  const unsigned int* c2p = CsU + (cgl + 32) * 36;
  const unsigned int* c3p = CsU + (cgl + 48) * 36;

  // ---- compute: 8 steps of 8 k ----
#pragma unroll 2
  for (int ks = 0; ks < 8; ++ks) {
    uint4v ra = *(const uint4v*)(rap + ks * 4);
    uint4v rb = *(const uint4v*)(rbp + ks * 4);
    uint4v wv = *(const uint4v*)(WsU + ks * 4);
    {
      uint4v cv = *(const uint4v*)(c0p + ks * 4);
#pragma unroll
      for (int p = 0; p < 4; ++p) {
        gelu_pair(accA0, ra[p], cv[p], wv[p]);
        gelu_pair(accB0, rb[p], cv[p], wv[p]);
      }
    }
    {
      uint4v cv = *(const uint4v*)(c1p + ks * 4);
#pragma unroll
      for (int p = 0; p < 4; ++p) {
        gelu_pair(accA1, ra[p], cv[p], wv[p]);
        gelu_pair(accB1, rb[p], cv[p], wv[p]);
      }
    }
    {
      uint4v cv = *(const uint4v*)(c2p + ks * 4);
#pragma unroll
      for (int p = 0; p < 4; ++p) {
        gelu_pair(accA2, ra[p], cv[p], wv[p]);
        gelu_pair(accB2, rb[p], cv[p], wv[p]);
      }
    }
    {
      uint4v cv = *(const uint4v*)(c3p + ks * 4);
#pragma unroll
      for (int p = 0; p < 4; ++p) {
        gelu_pair(accA3, ra[p], cv[p], wv[p]);
        gelu_pair(accB3, rb[p], cv[p], wv[p]);
      }
    }
  }

  // ---- epilogue: 8 partial sums -> atomics (24 contributions/addr) ----
  const size_t rowA = (size_t)(bz * 256 + it * 32 + 2 * rg);
  const size_t base = rowA * 256 + jt * 64 + cgl;
  unsafeAtomicAdd(&outm[base +  0], accA0);
  unsafeAtomicAdd(&outm[base + 16], accA1);
  unsafeAtomicAdd(&outm[base + 32], accA2);
  unsafeAtomicAdd(&outm[base + 48], accA3);
  unsafeAtomicAdd(&outm[base + 256 +  0], accB0);
  unsafeAtomicAdd(&outm[base + 256 + 16], accB1);
  unsafeAtomicAdd(&outm[base + 256 + 32], accB2);
  unsafeAtomicAdd(&outm[base + 256 + 48], accB3);
}

// ---------------- launch ----------------
extern "C" void kernel_launch(void* const* d_in, const int* in_sizes, int n_in,
                              void* d_out, int out_size, void* d_ws, size_t ws_size,
                              hipStream_t stream) {
  const float* hidden  = (const float*)d_in[0];
  const float* w_start = (const float*)d_in[1];
  const float* b_start = (const float*)d_in[2];
  const float* w_end   = (const float*)d_in[3];
  const float* b_end   = (const float*)d_in[4];
  const float* w1      = (const float*)d_in[5];
  const float* b1      = (const float*)d_in[6];
  const float* w2      = (const float*)d_in[7];
  const float* b2      = (const float*)d_in[8];

  float* out = (float*)d_out;
  char* ws = (char*)d_ws;
  unsigned short* wsR = (unsigned short*)(ws);             // 1,572,864 B
  unsigned short* wsC = (unsigned short*)(ws + 1572864);   // 1,572,864 B (3 MB total)

  proj_kernel<<<dim3(48, 17), dim3(256), 0, stream>>>(
      hidden, w1, b1, wsR, wsC, w_start, b_start, w_end, b_end, b2, out);
  match_kernel<<<dim3(4, 8, 48), dim3(256), 0, stream>>>(wsR, wsC, w2, out + 1024);
}